// Round 1
// 364.879 us; speedup vs baseline: 1.0479x; 1.0479x over previous
//
#include <hip/hip_runtime.h>

typedef unsigned short u16;
typedef unsigned int   u32;
typedef float f32x4 __attribute__((ext_vector_type(4)));
typedef short s16x8 __attribute__((ext_vector_type(8)));

#define NB    65536
#define K1    512
#define N1    1152
#define G1D   384
#define K2    384
#define G2D   16
#define NL    256

__device__ inline u16 f2bf(float f) {
  u32 u = __float_as_uint(f);
  u += 0x7fffu + ((u >> 16) & 1u);
  return (u16)(u >> 16);
}
__device__ inline float bf2f(u16 h) { return __uint_as_float(((u32)h) << 16); }
__device__ inline float sigmoidf_(float x) { return 1.0f / (1.0f + __expf(-x)); }
__device__ inline float tanhf_(float x) {
  float e = __expf(2.0f * fabsf(x));
  float t = 1.0f - 2.0f / (e + 1.0f);
  return copysignf(t, x);
}

// async global->LDS, 16B per lane; LDS dest must be wave-uniform base + lane*16
__device__ inline void gld16(const u16* g, u16* l) {
  __builtin_amdgcn_global_load_lds(
      (const __attribute__((address_space(1))) void*)g,
      (__attribute__((address_space(3))) void*)l, 16, 0, 0);
}

// ---- prep: concat x1|x2 -> bf16 A (NB x 512) ----
__global__ void prep_a(const float* __restrict__ x1, const float* __restrict__ x2,
                       u16* __restrict__ Abf) {
  int t = blockIdx.x * 256 + threadIdx.x;   // 8 elems/thread
  int i = t * 8;
  int row = i >> 9, col = i & 511;
  const float* src = (col < 384) ? (x1 + row * 384 + col) : (x2 + row * 128 + (col - 384));
  float4 v0 = ((const float4*)src)[0];
  float4 v1 = ((const float4*)src)[1];
  union { uint4 v; u16 u[8]; } o;
  o.u[0] = f2bf(v0.x); o.u[1] = f2bf(v0.y); o.u[2] = f2bf(v0.z); o.u[3] = f2bf(v0.w);
  o.u[4] = f2bf(v1.x); o.u[5] = f2bf(v1.y); o.u[6] = f2bf(v1.z); o.u[7] = f2bf(v1.w);
  *(uint4*)(Abf + i) = o.v;
}

// ---- prep: W1 [512][1152] f32 -> FRAGMENT-MAJOR bf16 ----
// Layout: frag(g, ut, kt) is 1KB: 64 lanes x 16B. lane = (u&15) + quad*16 holds
// B[u = ut*16 + (u&15)][k = kt*32 + quad*8 + e], e=0..7.
// Element offset = (((g*24+ut)*16 + kt)*64 + quad*16 + (u&15)) * 8 + e.
__global__ __launch_bounds__(256) void prep_wt1(const float* __restrict__ w,
                                                u16* __restrict__ wt) {
  __shared__ float tile[64][65];
  const int nt = blockIdx.x * 64;    // 18 blocks (384/64=6 per gate: no gate straddle)
  const int ktb = blockIdx.y * 64;   // 8
  const int tr = threadIdx.x >> 4;
  const int tc = (threadIdx.x & 15) * 4;
#pragma unroll
  for (int p = 0; p < 4; p++) {
    int k = ktb + p * 16 + tr;
    float4 v = *(const float4*)(w + (long)k * N1 + nt + tc);
    tile[p * 16 + tr][tc + 0] = v.x;
    tile[p * 16 + tr][tc + 1] = v.y;
    tile[p * 16 + tr][tc + 2] = v.z;
    tile[p * 16 + tr][tc + 3] = v.w;
  }
  __syncthreads();
  const int nl = threadIdx.x >> 3;        // 0..31
  const int kc = (threadIdx.x & 7) * 8;   // 8 consecutive k, same quad
#pragma unroll
  for (int p = 0; p < 2; p++) {
    int n = nl + p * 32;
    int c = nt + n;                 // global column 0..1151
    int g = c / 384;
    int urem = c - g * 384;
    int ut = urem >> 4, u16c = urem & 15;
    int k0 = ktb + kc;
    int kt = k0 >> 5, qd = (k0 >> 3) & 3;
    union { uint4 v; u16 u[8]; } o;
#pragma unroll
    for (int j = 0; j < 8; j++) o.u[j] = f2bf(tile[kc + j][n]);
    long off = ((long)((g * 24 + ut) * 16 + kt) * 64 + qd * 16 + u16c) * 8;
    *(uint4*)(wt + off) = o.v;
  }
}

// ---- prep: small transpose+cast weight w[K][N] -> wt[N][K] bf16 (W2) ----
__global__ void prep_wt(const float* __restrict__ w, u16* __restrict__ wt, int K, int N) {
  int n = blockIdx.x;
  int k0 = threadIdx.x * 8;
  if (k0 >= K) return;
  union { uint4 v; u16 u[8]; } o;
#pragma unroll
  for (int j = 0; j < 8; j++) o.u[j] = f2bf(w[(k0 + j) * N + n]);
  *(uint4*)(wt + n * K + k0) = o.v;
}

// ---- FUSED GEMM1 + gates: H1 = gru1_gates(A @ W1^T) ----
// v2 pipeline: A via 4-deep LDS buffers staged 2 k-steps ahead with
// global_load_lds; B direct global->reg from fragment-major W1t (L2-resident),
// register double-buffered 1 step ahead. ONE raw s_barrier per k-step, counted
// vmcnt (never 0 in the main loop). setprio(1) around the MFMA cluster.
__global__ __launch_bounds__(256, 2) void gemm1gate(const u16* __restrict__ A,
                                                    const u16* __restrict__ Bf,
                                                    const float* __restrict__ bias,
                                                    u16* __restrict__ H1) {
  __shared__ u16 As[4][128 * 32];   // 32 KB, 4-deep
  const int tid = threadIdx.x;
  const int wave = tid >> 6, lane = tid & 63;
  const int quad = lane >> 4, l16 = lane & 15;

  // XCD swizzle: 64 m-stripes per XCD, 6 consecutive u-blocks per stripe.
  const int id = blockIdx.x;
  const int xcd = id & 7;
  const int s = id >> 3;          // 0..383
  const int sd6 = s / 6;          // 0..63
  const int ublk = s - sd6 * 6;   // 0..5
  const int mbase = (xcd * 64 + sd6) * 128;
  const int ucbase = ublk * 64;

  const int wm = (wave & 1) * 64, wu = (wave >> 1) * 32;
  const int ut0 = ublk * 4 + (wave >> 1) * 2;   // base u-tile (16-wide) for this wave

  f32x4 acc[3][4][2];
#pragma unroll
  for (int g = 0; g < 3; g++)
#pragma unroll
    for (int i = 0; i < 4; i++)
#pragma unroll
      for (int j = 0; j < 2; j++)
#pragma unroll
        for (int r = 0; r < 4; r++) acc[g][i][j][r] = 0.0f;

  // A staging: thread -> row r0=tid>>2, k-chunk swizzled by (r0>>1)&3
  const int r0 = tid >> 2;
  const int kcg = ((tid & 3) ^ ((r0 >> 1) & 3)) * 8;
  const u16* Aptr  = A + (long)(mbase + r0) * K1 + kcg;
  const u16* Aptr2 = Aptr + 64 * K1;
  const u16* Bl = Bf + lane * 8;   // per-lane 16B within each 1KB fragment

  // A fragment read offsets within one LDS buffer
  int aoff[4];
#pragma unroll
  for (int i = 0; i < 4; i++) {
    int ra = wm + i * 16 + l16;
    aoff[i] = ra * 32 + ((quad ^ ((ra >> 1) & 3)) << 3);
  }

  // prologue: B(0) -> regs, then stage A(0), A(1) into buffers 0,1
  s16x8 bn[3][2];
#pragma unroll
  for (int g = 0; g < 3; g++)
#pragma unroll
    for (int j = 0; j < 2; j++)
      bn[g][j] = *(const s16x8*)(Bl + (long)((g * 24 + ut0 + j) * 16 + 0) * 512);
  asm volatile("" ::: "memory");
  gld16(Aptr,       &As[0][tid * 8]);
  gld16(Aptr2,      &As[0][2048 + tid * 8]);
  gld16(Aptr + 32,  &As[1][tid * 8]);
  gld16(Aptr2 + 32, &As[1][2048 + tid * 8]);

#pragma unroll
  for (int t = 0; t < 16; ++t) {
    // current B = what we prefetched last iter
    s16x8 bcur[3][2];
#pragma unroll
    for (int g = 0; g < 3; g++)
#pragma unroll
      for (int j = 0; j < 2; j++) bcur[g][j] = bn[g][j];

    // prefetch next B (k-step t+1) -- issued inside [prev wait .. fence] window
    if (t < 15) {
      const int tb = t + 1;
#pragma unroll
      for (int g = 0; g < 3; g++)
#pragma unroll
        for (int j = 0; j < 2; j++)
          bn[g][j] = *(const s16x8*)(Bl + (long)((g * 24 + ut0 + j) * 16 + tb) * 512);
    }
    asm volatile("" ::: "memory");
    // stage A (k-step t+2), 2 ahead
    if (t < 14) {
      const int ta = t + 2;
      gld16(Aptr  + ta * 32, &As[(t + 2) & 3][tid * 8]);
      gld16(Aptr2 + ta * 32, &As[(t + 2) & 3][2048 + tid * 8]);
    }
    // counted wait: retire A(t) (and older); leave prefetches in flight.
    // steady state: younger-than-A(t) = B(t+1)6 + A(t+1)2 + B(t+2)... = 16
    if (t == 0)       asm volatile("s_waitcnt vmcnt(10)" ::: "memory");
    else if (t < 14)  asm volatile("s_waitcnt vmcnt(16)" ::: "memory");
    else if (t == 14) asm volatile("s_waitcnt vmcnt(14)" ::: "memory");
    else              asm volatile("s_waitcnt vmcnt(6)"  ::: "memory");
    __builtin_amdgcn_s_barrier();
    asm volatile("" ::: "memory");

    const u16* buf = &As[t & 3][0];
    s16x8 af[4];
#pragma unroll
    for (int i = 0; i < 4; i++) af[i] = *(const s16x8*)(buf + aoff[i]);

    __builtin_amdgcn_s_setprio(1);
#pragma unroll
    for (int g = 0; g < 3; g++) {
#pragma unroll
      for (int mi = 0; mi < 4; mi++) {
        acc[g][mi][0] = __builtin_amdgcn_mfma_f32_16x16x32_bf16(af[mi], bcur[g][0], acc[g][mi][0], 0, 0, 0);
        acc[g][mi][1] = __builtin_amdgcn_mfma_f32_16x16x32_bf16(af[mi], bcur[g][1], acc[g][mi][1], 0, 0, 0);
      }
    }
    __builtin_amdgcn_s_setprio(0);
  }

  // epilogue: gates
#pragma unroll
  for (int j = 0; j < 2; j++) {
    int u = ucbase + wu + j * 16 + l16;
    float bz = bias[u] + bias[1152 + u];
    float br = bias[384 + u] + bias[1536 + u];
    float bh0 = bias[768 + u];
    float bh1 = bias[1920 + u];
#pragma unroll
    for (int mi = 0; mi < 4; mi++) {
#pragma unroll
      for (int rr = 0; rr < 4; rr++) {
        int row = mbase + wm + mi * 16 + quad * 4 + rr;
        float z  = sigmoidf_(acc[0][mi][j][rr] + bz);
        float rg = sigmoidf_(acc[1][mi][j][rr] + br);
        float hc = tanhf_(acc[2][mi][j][rr] + bh0 + rg * bh1);
        H1[(long)row * G1D + u] = f2bf((1.0f - z) * hc);
      }
    }
  }
}

// ---- FUSED GEMM2 + gates + FC + softmax ----
__global__ __launch_bounds__(256) void gemm2fc(const u16* __restrict__ H1b,
                                               const u16* __restrict__ W2t,
                                               const float* __restrict__ bias2,
                                               const float* __restrict__ w1,
                                               const float* __restrict__ fb1,
                                               const float* __restrict__ w2,
                                               const float* __restrict__ fb2,
                                               const float* __restrict__ g1,
                                               const float* __restrict__ g2,
                                               float* __restrict__ out) {
  __shared__ u16 As[128 * 32];      // 8 KB
  __shared__ u16 Bs[48 * 32];       // 3 KB
  __shared__ float h2s[128 * 17];   // 8.5 KB
  const int tid = threadIdx.x;
  const int wave = tid >> 6, lane = tid & 63;
  const int quad = lane >> 4, l16 = lane & 15;
  const int mbase = blockIdx.x * 128;

  f32x4 acc[2][3];
#pragma unroll
  for (int i = 0; i < 2; i++)
#pragma unroll
    for (int j = 0; j < 3; j++)
#pragma unroll
      for (int r = 0; r < 4; r++) acc[i][j][r] = 0.0f;

  const int r0 = tid >> 2, kc = (tid & 3) * 8;
  const u16* Aptr = H1b + (long)(mbase + r0) * K2 + kc;

  for (int k0 = 0; k0 < K2; k0 += 32) {
    uint4 a0 = *(const uint4*)(Aptr + k0);
    uint4 a1 = *(const uint4*)(Aptr + 64 * K2 + k0);
    uint4 bv;
    if (tid < 192) bv = *(const uint4*)(W2t + r0 * K2 + k0 + kc);
    __syncthreads();
    *(uint4*)(&As[r0 * 32 + kc]) = a0;
    *(uint4*)(&As[(64 + r0) * 32 + kc]) = a1;
    if (tid < 192) *(uint4*)(&Bs[r0 * 32 + kc]) = bv;
    __syncthreads();
    s16x8 af[2], bfr[3];
#pragma unroll
    for (int mi = 0; mi < 2; mi++)
      af[mi] = *(const s16x8*)(&As[(wave * 32 + mi * 16 + l16) * 32 + quad * 8]);
#pragma unroll
    for (int ni = 0; ni < 3; ni++)
      bfr[ni] = *(const s16x8*)(&Bs[(ni * 16 + l16) * 32 + quad * 8]);
#pragma unroll
    for (int mi = 0; mi < 2; mi++)
#pragma unroll
      for (int ni = 0; ni < 3; ni++)
        acc[mi][ni] = __builtin_amdgcn_mfma_f32_16x16x32_bf16(af[mi], bfr[ni], acc[mi][ni], 0, 0, 0);
  }

  {
    const int u = l16;
    const float b0z = bias2[u],      b1z = bias2[48 + u];
    const float b0r = bias2[16 + u], b1r = bias2[64 + u];
    const float b0h = bias2[32 + u], b1h = bias2[80 + u];
#pragma unroll
    for (int mi = 0; mi < 2; mi++) {
#pragma unroll
      for (int rr = 0; rr < 4; rr++) {
        int row_l = wave * 32 + mi * 16 + quad * 4 + rr;
        float z  = sigmoidf_(acc[mi][0][rr] + b0z + b1z);
        float rg = sigmoidf_(acc[mi][1][rr] + b0r + b1r);
        float hc = tanhf_(acc[mi][2][rr] + b0h + rg * b1h);
        h2s[row_l * 17 + u] = (1.0f - z) * hc;
      }
    }
  }
  __syncthreads();

  // Phase 2: fc + softmax, wave-per-row (32 rows per wave)
#pragma unroll 1
  for (int r = 0; r < 32; r++) {
    int row_l = wave * 32 + r;
    float h[16];
#pragma unroll
    for (int uu = 0; uu < 16; uu++) h[uu] = h2s[row_l * 17 + uu];
    float e[4];
    float mx = -1e30f;
#pragma unroll
    for (int i = 0; i < 4; i++) {
      int c = i * 64 + lane;
      float a1 = fb1[c], a2 = fb2[c];
#pragma unroll
      for (int uu = 0; uu < 16; uu++) {
        a1 = fmaf(h[uu], w1[uu * 256 + c], a1);
        a2 = fmaf(h[uu], w2[uu * 256 + c], a2);
      }
      float d = g1[c] * tanhf_(a1) + g2[c] * tanhf_(a2);
      e[i] = d;
      mx = fmaxf(mx, d);
    }
#pragma unroll
    for (int off = 32; off >= 1; off >>= 1) mx = fmaxf(mx, __shfl_xor(mx, off, 64));
    float sum = 0.0f;
#pragma unroll
    for (int i = 0; i < 4; i++) { e[i] = __expf(e[i] - mx); sum += e[i]; }
#pragma unroll
    for (int off = 32; off >= 1; off >>= 1) sum += __shfl_xor(sum, off, 64);
    float inv = 1.0f / sum;
    float* orow = out + (long)(mbase + row_l) * NL;
#pragma unroll
    for (int i = 0; i < 4; i++) orow[i * 64 + lane] = e[i] * inv;
  }
}

extern "C" void kernel_launch(void* const* d_in, const int* in_sizes, int n_in,
                              void* d_out, int out_size, void* d_ws, size_t ws_size,
                              hipStream_t stream) {
  const float* x1   = (const float*)d_in[0];
  const float* x2   = (const float*)d_in[1];
  const float* w1k  = (const float*)d_in[2];   // gru1_kernel (512 x 1152)
  const float* b1g  = (const float*)d_in[4];   // gru1_bias (2 x 1152)
  const float* w2k  = (const float*)d_in[5];   // gru2_kernel (384 x 48)
  const float* b2g  = (const float*)d_in[7];   // gru2_bias (2 x 48)
  const float* fcw1 = (const float*)d_in[8];
  const float* fcb1 = (const float*)d_in[9];
  const float* fcw2 = (const float*)d_in[10];
  const float* fcb2 = (const float*)d_in[11];
  const float* fcg1 = (const float*)d_in[12];
  const float* fcg2 = (const float*)d_in[13];
  float* out = (float*)d_out;

  char* ws = (char*)d_ws;
  u16* Abf = (u16*)(ws + 0);            // 65536*512*2   = 67108864
  u16* W1t = (u16*)(ws + 67108864);     // 1152*512*2    = 1179648 (fragment-major)
  u16* H1  = (u16*)(ws + 68288512);     // 65536*384*2   = 50331648
  u16* W2t = (u16*)(ws + 118620160);    // 48*384*2      = 36864

  hipLaunchKernelGGL(prep_a, dim3(16384), dim3(256), 0, stream, x1, x2, Abf);
  hipLaunchKernelGGL(prep_wt1, dim3(18, 8), dim3(256), 0, stream, w1k, W1t);
  hipLaunchKernelGGL(prep_wt, dim3(48), dim3(64), 0, stream, w2k, W2t, 384, 48);
  hipLaunchKernelGGL(gemm1gate, dim3(3072), dim3(256), 0, stream, Abf, W1t, b1g, H1);
  hipLaunchKernelGGL(gemm2fc, dim3(512), dim3(256), 0, stream, H1, W2t, b2g,
                     fcw1, fcb1, fcw2, fcb2, fcg1, fcg2, out);
}